// Round 7
// baseline (569.036 us; speedup 1.0000x reference)
//
#include <hip/hip_runtime.h>
#include <cstdint>

// Sparse BasicBlock via bf16 MFMA implicit GEMM (32x32x16).
// Round 7: exploit the BINARY channel gate (vector, ~50% dense).
//   conv1: dense R5 structure, but epilogue writes u CHANNEL-COMPACTED per image
//          (slot = inv[img][co]; inactive channels skipped — they are zero).
//   conv2: R5 structure with DYNAMIC K: only nch = ceil(nact/16) chunks (~9 vs 16),
//          weights per-image gathered (wp2g) to match compact channel order.
//   wp2g overlays xm's workspace (xm dead after conv1) -> no extra ws.
//   xm,u layout: [img][slab32][row58][col58][c8] (halo zero); staging order ==
//   storage order => all global_load_lds coalesced.

#define EPS 1e-5f

constexpr int Bn = 32, Cc = 256, Hh = 56, Ww = 56;
constexpr int HW = Hh * Ww;                 // 3136
constexpr int PD = 58;                      // padded H/W
constexpr int PP = PD * PD;                 // 3364
constexpr int SLAB = PP * 8;                // elems per [row][col][c8] slab = 26912
constexpr int IMG_ELEMS = 32 * SLAB;        // 861184 elems per image
constexpr int WP_ELEMS = 2 * 16 * 9 * 2 * 128 * 8;   // 589824

typedef __bf16 bf16x8 __attribute__((ext_vector_type(8)));
typedef float  f32x16 __attribute__((ext_vector_type(16)));

// ---- pack x*mask_dilate -> chunk-major staged bf16, halo zeros ----
__global__ void pack_xm(const float* __restrict__ x, const float* __restrict__ md,
                        __bf16* __restrict__ xm) {
    int prow = blockIdx.x, img = blockIdx.y;
    int gy = prow - 1;
    bool rv = (unsigned)gy < 56u;
    for (int u = threadIdx.x; u < 32 * 64; u += 256) {
        int cg = u >> 6, pcol = u & 63;
        if (pcol >= PD) continue;
        int gx = pcol - 1;
        bf16x8 v = {};
        if (rv && (unsigned)gx < 56u) {
            float mdv = md[img * HW + gy * 56 + gx];
            const float* xp = x + ((size_t)img * Cc + cg * 8) * HW + gy * 56 + gx;
            #pragma unroll
            for (int j = 0; j < 8; ++j)
                v[j] = (__bf16)(xp[(size_t)j * HW] * mdv);
        }
        *(bf16x8*)&xm[(size_t)(img * 32 + cg) * SLAB + (prow * PD + pcol) * 8] = v;
    }
}

// ---- per-image active-channel maps from binary vector ----
__global__ void cmap_kern(const float* __restrict__ vec, int* __restrict__ act,
                          int* __restrict__ inv, int* __restrict__ meta) {
    int img = threadIdx.x;
    if (img >= Bn) return;
    int n = 0;
    for (int c = 0; c < Cc; ++c) {
        if (vec[img * Cc + c] != 0.f) { act[img * Cc + n] = c; inv[img * Cc + c] = n; ++n; }
        else inv[img * Cc + c] = -1;
    }
    for (int k = n; k < Cc; ++k) act[img * Cc + k] = 0;
    meta[img] = n;                 // nact
    meta[Bn + img] = (n + 15) >> 4; // nch
}

// ---- zero u: full-zero slabs containing sentinel slots, halo-zero the rest ----
__global__ void zero_u(__bf16* __restrict__ u, const int* __restrict__ meta) {
    int img = blockIdx.x;
    int nact = meta[img], nch = meta[Bn + img];
    __bf16* base = u + (size_t)img * IMG_ELEMS;
    bf16x8 z = {};
    int nslab = 2 * nch;
    for (int s = 0; s < nslab; ++s) {
        __bf16* sb = base + (size_t)s * SLAB;
        if (8 * s + 7 >= nact) {
            for (int t = threadIdx.x; t < PP; t += 256)
                *(bf16x8*)&sb[t * 8] = z;
        } else {
            for (int t = threadIdx.x; t < 228; t += 256) {
                int prow, pcol;
                if (t < 58)       { prow = 0;        pcol = t; }
                else if (t < 116) { prow = 57;       pcol = t - 58; }
                else if (t < 172) { prow = t - 115;  pcol = 0; }
                else              { prow = t - 171;  pcol = 57; }
                *(bf16x8*)&sb[(prow * PD + pcol) * 8] = z;
            }
        }
    }
}

// ---- pack conv1 weights (dense): w1[co][ci][tap] f32 -> wp1[coblk][chunk][tap][half][co128][8ci] ----
__global__ void pack_w1(const float* __restrict__ w1, __bf16* __restrict__ wp1) {
    int id = blockIdx.x * 256 + threadIdx.x;     // < 589824
    int j = id & 7; int t = id >> 3;
    int col = t & 127; t >>= 7;
    int half = t & 1; t >>= 1;
    int tap = t % 9; t /= 9;
    int chunk = t & 15; int coblk = t >> 4;
    int co = coblk * 128 + col;
    int ci = chunk * 16 + half * 8 + j;
    wp1[id] = (__bf16)(w1[((size_t)co * Cc + ci) * 9 + tap]);
}

// ---- per-image gathered conv2 weights: ci dimension remapped to compact slots ----
// wp2g[img][coblk][chunk][tap][half][co128][8slot]; zero for sentinel slots.
__global__ void gather_w2(const float* __restrict__ w2, const int* __restrict__ act,
                          const int* __restrict__ meta, __bf16* __restrict__ wp2g) {
    int img = blockIdx.y;
    int id = blockIdx.x * 256 + threadIdx.x;     // < 589824
    int nact = meta[img], nch = meta[Bn + img];
    int j = id & 7; int t = id >> 3;
    int col = t & 127; t >>= 7;
    int half = t & 1; t >>= 1;
    int tap = t % 9; t /= 9;
    int chunk = t & 15; int coblk = t >> 4;
    if (chunk >= nch) return;                    // never staged
    int kslot = chunk * 16 + half * 8 + j;
    float v = 0.f;
    if (kslot < nact) {
        int co = coblk * 128 + col;
        v = w2[((size_t)co * Cc + act[img * Cc + kslot]) * 9 + tap];
    }
    wp2g[(size_t)img * WP_ELEMS + id] = (__bf16)v;
}

// ---- fold BN params ----
__global__ void bn_prep(const float* g1, const float* b1, const float* m1, const float* v1,
                        const float* g2, const float* b2, const float* m2, const float* v2,
                        float* binv1, float* bbeta1, float* binv2, float* bbeta2) {
    int c = threadIdx.x;
    float i1 = g1[c] * rsqrtf(v1[c] + EPS);
    binv1[c] = i1; bbeta1[c] = b1[c] - m1[c] * i1;
    float i2 = g2[c] * rsqrtf(v2[c] + EPS);
    binv2[c] = i2; bbeta2[c] = b2[c] - m2[c] * i2;
}

__device__ __forceinline__ void gl_lds16(const __bf16* g, __bf16* l) {
    __builtin_amdgcn_global_load_lds(
        (const __attribute__((address_space(1))) void*)g,
        (__attribute__((address_space(3))) void*)l, 16, 0, 0);
}

template <bool C1>
__global__ __launch_bounds__(256, 3)
void conv_kern(const __bf16* __restrict__ src,   // xm (conv1) or compact u (conv2)
               const __bf16* __restrict__ wp,    // wp1 (dense) or wp2g (per-image)
               const float* __restrict__ maskg,  // mask [B,HW]
               const float* __restrict__ vec,    // vector [B,C] (conv1 only)
               const int* __restrict__ inv,      // channel->slot (conv1 only)
               const int* __restrict__ meta,     // nact[32], nch[32]
               const float* __restrict__ binv, const float* __restrict__ bbeta,
               const float* __restrict__ xin,    // identity x NCHW f32 (conv2 only)
               void* __restrict__ dstv) {
    constexpr int SINB = 2 * 4 * 66 * 8;         // 4224 elems = 8448 B
    constexpr int SWB  = 9 * 2 * 128 * 8;        // 18432 elems = 36864 B
    __shared__ __align__(16) __bf16 s_in[SINB];
    __shared__ __align__(16) __bf16 s_w[SWB];    // total 45312 B -> 3 blocks/CU

    const int tid = threadIdx.x;
    const int lane = tid & 63, wave = tid >> 6;  // 4 waves
    const int xlane = lane & 31, halfid = lane >> 5;
    const int pxg = wave >> 1, cog = wave & 1;   // 2 px rows x 2 co halves

    // XCD-bijective swizzle (1792 = 8*224)
    const int bid = blockIdx.x;
    const int wg = (bid & 7) * 224 + (bid >> 3);
    const int img = wg / 56;
    const int t = wg - img * 56;
    const int y0 = (t >> 1) * 2;                 // band of 2 output rows
    const int coblk = t & 1;
    const int co0c = coblk * 128;

    const int nloop = C1 ? 16 : meta[Bn + img];  // conv2: dynamic K chunks

    f32x16 acc[2][2];
    #pragma unroll
    for (int a = 0; a < 2; ++a)
        #pragma unroll
        for (int b = 0; b < 2; ++b)
            #pragma unroll
            for (int r = 0; r < 16; ++r) acc[a][b][r] = 0.f;

    const __bf16* wblk = C1 ? (wp + (size_t)coblk * (16 * SWB))
                            : (wp + (size_t)img * WP_ELEMS + (size_t)coblk * (16 * SWB));
    const float* maskp = maskg + (size_t)img * HW;
    const __bf16* srcimg = src + (size_t)img * IMG_ELEMS;

    // ---- staging: storage order == enumeration order; all loads coalesced ----
    auto STAGE_IN = [&](int chunk) {             // 528 units
        const __bf16* slab = srcimg + (size_t)chunk * (2 * SLAB);
        #pragma unroll
        for (int k = 0; k < 3; ++k) {
            int u0 = wave * 64 + k * 256;
            int u = u0 + lane;
            if (u < 528) {
                int half = u / 264, rem = u - half * 264;
                int row = rem / 66, xx = rem - row * 66;
                int pcol = xx < PD ? xx : PD - 1;   // clamp: feeds dead outputs only
                gl_lds16(slab + ((size_t)half * SLAB) + ((y0 + row) * PD + pcol) * 8,
                         &s_in[u0 * 8]);
            }
        }
    };
    auto STAGE_W = [&](int chunk) {              // 2304 units = 9 * 256
        const __bf16* g = wblk + (size_t)chunk * SWB;
        #pragma unroll
        for (int k = 0; k < 9; ++k) {
            int u0 = wave * 64 + k * 256;
            gl_lds16(g + (size_t)(u0 + lane) * 8, &s_w[u0 * 8]);
        }
    };

    for (int c = 0; c < nloop; ++c) {
        STAGE_W(c);
        STAGE_IN(c);
        asm volatile("s_waitcnt vmcnt(0)" ::: "memory");
        __builtin_amdgcn_sched_barrier(0);
        __builtin_amdgcn_s_barrier();
        __builtin_amdgcn_sched_barrier(0);

        __builtin_amdgcn_s_setprio(1);
        #pragma unroll
        for (int kh = 0; kh < 3; ++kh)
            #pragma unroll
            for (int kw = 0; kw < 3; ++kw) {
                const int tap = kh * 3 + kw;
                bf16x8 wf[2], inf[2];
                #pragma unroll
                for (int jt = 0; jt < 2; ++jt)
                    wf[jt] = *(const bf16x8*)&s_w[((tap * 2 + halfid) * 128 +
                                                   (cog * 2 + jt) * 32 + xlane) * 8];
                #pragma unroll
                for (int it = 0; it < 2; ++it) {
                    int yy = pxg + kh;           // 0..3 within 4-row window
                    int xx = it * 32 + xlane + kw;
                    inf[it] = *(const bf16x8*)&s_in[((halfid * 4 + yy) * 66 + xx) * 8];
                }
                #pragma unroll
                for (int it = 0; it < 2; ++it)
                    #pragma unroll
                    for (int jt = 0; jt < 2; ++jt) {
                        if constexpr (C1)
                            acc[it][jt] = __builtin_amdgcn_mfma_f32_32x32x16_bf16(
                                inf[it], wf[jt], acc[it][jt], 0, 0, 0);
                        else
                            acc[it][jt] = __builtin_amdgcn_mfma_f32_32x32x16_bf16(
                                wf[jt], inf[it], acc[it][jt], 0, 0, 0);
                    }
            }
        __builtin_amdgcn_s_setprio(0);
        __builtin_amdgcn_sched_barrier(0);
        __builtin_amdgcn_s_barrier();            // all waves done reading buffers
        __builtin_amdgcn_sched_barrier(0);
    }

    // ---- epilogue ----
    const int y = y0 + pxg;                      // this wave's single output row
    if constexpr (C1) {
        // D: row = pixel-x, col(lane&31) = co. Store u CHANNEL-COMPACTED bf16.
        __bf16* u = (__bf16*)dstv;
        float iv[2], bt[2], vv[2]; int slt[2]; size_t slb[2];
        #pragma unroll
        for (int jt = 0; jt < 2; ++jt) {
            int co = co0c + (cog * 2 + jt) * 32 + xlane;
            iv[jt] = binv[co];
            bt[jt] = bbeta[co];
            vv[jt] = vec[img * Cc + co];
            slt[jt] = inv[img * Cc + co];        // -1 if channel inactive
            int s = slt[jt] < 0 ? 0 : slt[jt];
            slb[jt] = (size_t)(img * 32 + (s >> 3)) * SLAB + (s & 7);
        }
        #pragma unroll
        for (int it = 0; it < 2; ++it) {
            int xb = it * 32;
            #pragma unroll
            for (int reg = 0; reg < 16; ++reg) {
                int x = xb + (reg & 3) + 8 * (reg >> 2) + 4 * halfid;
                if (x < 56) {
                    float mv = maskp[y * 56 + x];
                    int poff = ((y + 1) * PD + (x + 1)) * 8;
                    #pragma unroll
                    for (int jt = 0; jt < 2; ++jt) {
                        if (slt[jt] >= 0) {
                            float o = fmaxf(fmaf(acc[it][jt][reg], iv[jt], bt[jt]), 0.f)
                                      * mv * vv[jt];
                            u[slb[jt] + poff] = (__bf16)o;
                        }
                    }
                }
            }
        }
    } else {
        // D: row = co, col(lane&31) = pixel. Store NCHW f32 + identity+relu.
        float* outp = (float*)dstv;
        int xa[2]; float mva[2]; bool ok[2];
        #pragma unroll
        for (int it = 0; it < 2; ++it) {
            xa[it] = it * 32 + xlane;
            ok[it] = xa[it] < 56;
            mva[it] = ok[it] ? maskp[y * 56 + xa[it]] : 0.f;
        }
        #pragma unroll
        for (int jt = 0; jt < 2; ++jt) {
            int cb = co0c + (cog * 2 + jt) * 32;
            #pragma unroll
            for (int rg = 0; rg < 4; ++rg) {
                int c4 = cb + 8 * rg + 4 * halfid;
                float4 iv4 = *(const float4*)&binv[c4];
                float4 bt4 = *(const float4*)&bbeta[c4];
                float ivv[4] = {iv4.x, iv4.y, iv4.z, iv4.w};
                float btv[4] = {bt4.x, bt4.y, bt4.z, bt4.w};
                #pragma unroll
                for (int j = 0; j < 4; ++j) {
                    int reg = rg * 4 + j;
                    int co = c4 + j;
                    size_t cbase = (size_t)(img * Cc + co) * HW;
                    #pragma unroll
                    for (int it = 0; it < 2; ++it) {
                        if (ok[it]) {
                            size_t oa = cbase + y * 56 + xa[it];
                            float ov = fmaxf(
                                xin[oa] + mva[it] * fmaf(acc[it][jt][reg], ivv[j], btv[j]),
                                0.f);
                            outp[oa] = ov;
                        }
                    }
                }
            }
        }
    }
}

extern "C" void kernel_launch(void* const* d_in, const int* in_sizes, int n_in,
                              void* d_out, int out_size, void* d_ws, size_t ws_size,
                              hipStream_t stream) {
    const float* x    = (const float*)d_in[0];
    const float* mask = (const float*)d_in[1];
    const float* md   = (const float*)d_in[2];
    const float* vec  = (const float*)d_in[3];
    const float* w1   = (const float*)d_in[4];
    const float* bn1g = (const float*)d_in[5];
    const float* bn1b = (const float*)d_in[6];
    const float* bn1m = (const float*)d_in[7];
    const float* bn1v = (const float*)d_in[8];
    const float* w2   = (const float*)d_in[9];
    const float* bn2g = (const float*)d_in[10];
    const float* bn2b = (const float*)d_in[11];
    const float* bn2m = (const float*)d_in[12];
    const float* bn2v = (const float*)d_in[13];
    float* out = (float*)d_out;

    const size_t npad = (size_t)Bn * IMG_ELEMS;  // 27,557,888 elems (55.1 MB bf16)
    __bf16* xm  = (__bf16*)d_ws;
    __bf16* u   = xm + npad;
    __bf16* wp1 = u + npad;
    int* act    = (int*)(wp1 + WP_ELEMS);
    int* invm   = act + Bn * Cc;
    int* meta   = invm + Bn * Cc;
    float* binv1  = (float*)(meta + 64);
    float* bbeta1 = binv1 + 256;
    float* binv2  = bbeta1 + 256;
    float* bbeta2 = binv2 + 256;
    __bf16* wp2g = xm;                           // overlay: xm dead after conv1

    pack_xm<<<dim3(PD, Bn), dim3(256), 0, stream>>>(x, md, xm);
    pack_w1<<<dim3(WP_ELEMS / 256), dim3(256), 0, stream>>>(w1, wp1);
    cmap_kern<<<dim3(1), dim3(64), 0, stream>>>(vec, act, invm, meta);
    zero_u<<<dim3(Bn), dim3(256), 0, stream>>>(u, meta);
    bn_prep<<<dim3(1), dim3(256), 0, stream>>>(bn1g, bn1b, bn1m, bn1v,
                                               bn2g, bn2b, bn2m, bn2v,
                                               binv1, bbeta1, binv2, bbeta2);

    conv_kern<true><<<dim3(1792), dim3(256), 0, stream>>>(
        xm, wp1, mask, vec, invm, meta, binv1, bbeta1, nullptr, u);
    gather_w2<<<dim3(WP_ELEMS / 256, Bn), dim3(256), 0, stream>>>(w2, act, meta, wp2g);
    conv_kern<false><<<dim3(1792), dim3(256), 0, stream>>>(
        u, wp2g, mask, nullptr, invm, meta, binv2, bbeta2, x, out);
}

// Round 9
// 503.005 us; speedup vs baseline: 1.1313x; 1.1313x over previous
//
#include <hip/hip_runtime.h>
#include <cstdint>

// Sparse BasicBlock via bf16 MFMA implicit GEMM (32x32x16), channel-compacted
// on BOTH gated dims (vector is binary ~50% dense):
//   conv1: N-compacted — only active output channels computed (blocks with
//          co0c >= nact exit); per-image weights wp1g gathered along co at
//          16B-unit granularity; epilogue stores slot-direct compact u.
//   conv2: K-compacted — dynamic nch = ceil(nact/16) chunks; per-image weights
//          wp2g gathered via transposed wpT[ci][tap][co] (coalesced reads,
//          16B coalesced writes).
// Glue kernels are parallel/coalesced (R7 lesson: serial cmap + scattered
// gather cost ~170us). wp1g overlays d_out (dead until conv2 epilogue fully
// overwrites); wp2g overlays xm (dead after conv1).
//   xm,u layout: [img][slab32][row58][col58][c8] (halo zero); staging order ==
//   storage order => all global_load_lds coalesced.

#define EPS 1e-5f

constexpr int Bn = 32, Cc = 256, Hh = 56, Ww = 56;
constexpr int HW = Hh * Ww;                 // 3136
constexpr int PD = 58;                      // padded H/W
constexpr int PP = PD * PD;                 // 3364
constexpr int SLAB = PP * 8;                // elems per [row][col][c8] slab = 26912
constexpr int IMG_ELEMS = 32 * SLAB;        // 861184 elems per image
constexpr int WP_ELEMS = 2 * 16 * 9 * 2 * 128 * 8;   // 589824 (= 1.18 MB bf16)

typedef __bf16 bf16x8 __attribute__((ext_vector_type(8)));
typedef float  f32x16 __attribute__((ext_vector_type(16)));

// ---- pack x*mask_dilate -> chunk-major staged bf16, halo zeros ----
__global__ void pack_xm(const float* __restrict__ x, const float* __restrict__ md,
                        __bf16* __restrict__ xm) {
    int prow = blockIdx.x, img = blockIdx.y;
    int gy = prow - 1;
    bool rv = (unsigned)gy < 56u;
    for (int u = threadIdx.x; u < 32 * 64; u += 256) {
        int cg = u >> 6, pcol = u & 63;
        if (pcol >= PD) continue;
        int gx = pcol - 1;
        bf16x8 v = {};
        if (rv && (unsigned)gx < 56u) {
            float mdv = md[img * HW + gy * 56 + gx];
            const float* xp = x + ((size_t)img * Cc + cg * 8) * HW + gy * 56 + gx;
            #pragma unroll
            for (int j = 0; j < 8; ++j)
                v[j] = (__bf16)(xp[(size_t)j * HW] * mdv);
        }
        *(bf16x8*)&xm[(size_t)(img * 32 + cg) * SLAB + (prow * PD + pcol) * 8] = v;
    }
}

// ---- wave-parallel active-channel map (ballot + popc), one wave per image ----
__global__ void cmap_kern(const float* __restrict__ vec, int* __restrict__ act,
                          int* __restrict__ meta) {
    int img = blockIdx.x, lane = threadIdx.x;    // 64 threads
    int base = 0;
    #pragma unroll
    for (int g = 0; g < 4; ++g) {
        int c = g * 64 + lane;
        bool a = vec[img * Cc + c] != 0.f;
        unsigned long long m = __ballot(a);
        int pos = __popcll(m & ((1ull << lane) - 1ull));
        if (a) act[img * Cc + base + pos] = c;
        base += (int)__popcll(m);
    }
    __syncthreads();
    // defensive: zero-fill unused tail (all consumers guard on nact, but be safe)
    for (int k = base + lane; k < Cc; k += 64) act[img * Cc + k] = 0;
    if (lane == 0) { meta[img] = base; meta[Bn + img] = (base + 15) >> 4; }
}

// ---- zero u: full-zero slabs containing sentinel slots, halo-zero the rest ----
__global__ void zero_u(__bf16* __restrict__ u, const int* __restrict__ meta) {
    int img = blockIdx.x;
    int nact = meta[img], nch = meta[Bn + img];
    __bf16* base = u + (size_t)img * IMG_ELEMS;
    bf16x8 z = {};
    int nslab = 2 * nch;
    for (int s = 0; s < nslab; ++s) {
        __bf16* sb = base + (size_t)s * SLAB;
        if (8 * s + 7 >= nact) {
            for (int t = threadIdx.x; t < PP; t += 256)
                *(bf16x8*)&sb[t * 8] = z;
        } else {
            for (int t = threadIdx.x; t < 228; t += 256) {
                int prow, pcol;
                if (t < 58)       { prow = 0;        pcol = t; }
                else if (t < 116) { prow = 57;       pcol = t - 58; }
                else if (t < 172) { prow = t - 115;  pcol = 0; }
                else              { prow = t - 171;  pcol = 57; }
                *(bf16x8*)&sb[(prow * PD + pcol) * 8] = z;
            }
        }
    }
}

// ---- pack conv1 weights (dense): w1[co][ci][tap] -> wp1[coblk][chunk][tap][half][co128][8ci] ----
__global__ void pack_w1(const float* __restrict__ w1, __bf16* __restrict__ wp1) {
    int id = blockIdx.x * 256 + threadIdx.x;
    int j = id & 7; int t = id >> 3;
    int col = t & 127; t >>= 7;
    int half = t & 1; t >>= 1;
    int tap = t % 9; t /= 9;
    int chunk = t & 15; int coblk = t >> 4;
    int co = coblk * 128 + col;
    int ci = chunk * 16 + half * 8 + j;
    wp1[id] = (__bf16)(w1[((size_t)co * Cc + ci) * 9 + tap]);
}

// ---- transpose conv2 weights: w2[co][ci][tap] -> wpT[ci][tap][co] bf16 ----
__global__ void pack_w2T(const float* __restrict__ w2, __bf16* __restrict__ wpT) {
    int id = blockIdx.x * 256 + threadIdx.x;     // < 589824
    int co = id & 255; int t = id >> 8;
    int tap = t % 9; int ci = t / 9;
    wpT[id] = (__bf16)(w2[((size_t)co * Cc + ci) * 9 + tap]);
}

// ---- per-image conv1 weight gather along co (16B-unit granularity) ----
__global__ void gather_w1(const __bf16* __restrict__ wp1, const int* __restrict__ act,
                          const int* __restrict__ meta, __bf16* __restrict__ wp1g) {
    int img = blockIdx.y;
    int uidx = blockIdx.x * 256 + threadIdx.x;   // < 73728 units
    int nact = meta[img];
    int col = uidx & 127; int t = uidx >> 7;
    int half = t & 1; t >>= 1;
    int tap = t % 9; t /= 9;
    int chunk = t & 15; int coblk = t >> 4;
    if (coblk * 128 >= nact) return;             // whole co-block inactive: never staged
    int slot = coblk * 128 + col;
    bf16x8 v = {};
    if (slot < nact) {
        int co = act[img * Cc + slot];
        v = *(const bf16x8*)&wp1[(size_t)(((((co >> 7) * 16 + chunk) * 9 + tap) * 2 + half)
                                          * 128 + (co & 127)) * 8];
    }
    *(bf16x8*)&wp1g[(size_t)img * WP_ELEMS + (size_t)uidx * 8] = v;
}

// ---- per-image conv2 weight gather along ci (coalesced via wpT) ----
__global__ void gather_w2(const __bf16* __restrict__ wpT, const int* __restrict__ act,
                          const int* __restrict__ meta, __bf16* __restrict__ wp2g) {
    int img = blockIdx.y;
    int blk = blockIdx.x;                        // 32 = coblk*16 + chunk
    int coblk = blk >> 4, chunk = blk & 15;
    int nact = meta[img], nch = meta[Bn + img];
    if (chunk >= nch) return;                    // never staged
    int half = threadIdx.x >> 7, co = threadIdx.x & 127;
    int cog = coblk * 128 + co;
    int ci8[8];
    #pragma unroll
    for (int j = 0; j < 8; ++j) {
        int ks = chunk * 16 + half * 8 + j;
        ci8[j] = ks < nact ? act[img * Cc + ks] : -1;
    }
    #pragma unroll
    for (int tap = 0; tap < 9; ++tap) {
        bf16x8 v;
        #pragma unroll
        for (int j = 0; j < 8; ++j)
            v[j] = ci8[j] >= 0 ? wpT[(size_t)(ci8[j] * 9 + tap) * 256 + cog] : (__bf16)0.f;
        *(bf16x8*)&wp2g[(size_t)img * WP_ELEMS +
                        (size_t)((((coblk * 16 + chunk) * 9 + tap) * 2 + half) * 128 + co) * 8] = v;
    }
}

// ---- fold BN params ----
__global__ void bn_prep(const float* g1, const float* b1, const float* m1, const float* v1,
                        const float* g2, const float* b2, const float* m2, const float* v2,
                        float* binv1, float* bbeta1, float* binv2, float* bbeta2) {
    int c = threadIdx.x;
    float i1 = g1[c] * rsqrtf(v1[c] + EPS);
    binv1[c] = i1; bbeta1[c] = b1[c] - m1[c] * i1;
    float i2 = g2[c] * rsqrtf(v2[c] + EPS);
    binv2[c] = i2; bbeta2[c] = b2[c] - m2[c] * i2;
}

__device__ __forceinline__ void gl_lds16(const __bf16* g, __bf16* l) {
    __builtin_amdgcn_global_load_lds(
        (const __attribute__((address_space(1))) void*)g,
        (__attribute__((address_space(3))) void*)l, 16, 0, 0);
}

template <bool C1>
__global__ __launch_bounds__(256, 3)
void conv_kern(const __bf16* __restrict__ src,   // xm (conv1) or compact u (conv2)
               const __bf16* __restrict__ wp,    // wp1g / wp2g (both per-image)
               const float* __restrict__ maskg,  // mask [B,HW]
               const int* __restrict__ act,      // slot->channel (conv1 epilogue)
               const int* __restrict__ meta,     // nact[32], nch[32]
               const float* __restrict__ binv, const float* __restrict__ bbeta,
               const float* __restrict__ xin,    // identity x NCHW f32 (conv2 only)
               void* __restrict__ dstv) {
    constexpr int SINB = 2 * 4 * 66 * 8;         // 4224 elems = 8448 B
    constexpr int SWB  = 9 * 2 * 128 * 8;        // 18432 elems = 36864 B
    __shared__ __align__(16) __bf16 s_in[SINB];
    __shared__ __align__(16) __bf16 s_w[SWB];    // total 45312 B -> 3 blocks/CU

    const int tid = threadIdx.x;
    const int lane = tid & 63, wave = tid >> 6;  // 4 waves
    const int xlane = lane & 31, halfid = lane >> 5;
    const int pxg = wave >> 1, cog = wave & 1;   // 2 px rows x 2 co halves

    // XCD-bijective swizzle (1792 = 8*224)
    const int bid = blockIdx.x;
    const int wg = (bid & 7) * 224 + (bid >> 3);
    const int img = wg / 56;
    const int t = wg - img * 56;
    const int y0 = (t >> 1) * 2;                 // band of 2 output rows
    const int coblk = t & 1;
    const int co0c = coblk * 128;

    const int nact = meta[img];
    if constexpr (C1) { if (co0c >= nact) return; }   // inactive co-block
    const int nloop = C1 ? 16 : meta[Bn + img];       // conv2: dynamic K chunks

    f32x16 acc[2][2];
    #pragma unroll
    for (int a = 0; a < 2; ++a)
        #pragma unroll
        for (int b = 0; b < 2; ++b)
            #pragma unroll
            for (int r = 0; r < 16; ++r) acc[a][b][r] = 0.f;

    const __bf16* wblk = wp + (size_t)img * WP_ELEMS + (size_t)coblk * (16 * SWB);
    const float* maskp = maskg + (size_t)img * HW;
    const __bf16* srcimg = src + (size_t)img * IMG_ELEMS;

    // ---- staging: storage order == enumeration order; all loads coalesced ----
    auto STAGE_IN = [&](int chunk) {             // 528 units
        const __bf16* slab = srcimg + (size_t)chunk * (2 * SLAB);
        #pragma unroll
        for (int k = 0; k < 3; ++k) {
            int u0 = wave * 64 + k * 256;
            int u = u0 + lane;
            if (u < 528) {
                int half = u / 264, rem = u - half * 264;
                int row = rem / 66, xx = rem - row * 66;
                int pcol = xx < PD ? xx : PD - 1;   // clamp: feeds dead outputs only
                gl_lds16(slab + ((size_t)half * SLAB) + ((y0 + row) * PD + pcol) * 8,
                         &s_in[u0 * 8]);
            }
        }
    };
    auto STAGE_W = [&](int chunk) {              // 2304 units = 9 * 256
        const __bf16* g = wblk + (size_t)chunk * SWB;
        #pragma unroll
        for (int k = 0; k < 9; ++k) {
            int u0 = wave * 64 + k * 256;
            gl_lds16(g + (size_t)(u0 + lane) * 8, &s_w[u0 * 8]);
        }
    };

    for (int c = 0; c < nloop; ++c) {
        STAGE_W(c);
        STAGE_IN(c);
        asm volatile("s_waitcnt vmcnt(0)" ::: "memory");
        __builtin_amdgcn_sched_barrier(0);
        __builtin_amdgcn_s_barrier();
        __builtin_amdgcn_sched_barrier(0);

        __builtin_amdgcn_s_setprio(1);
        #pragma unroll
        for (int kh = 0; kh < 3; ++kh)
            #pragma unroll
            for (int kw = 0; kw < 3; ++kw) {
                const int tap = kh * 3 + kw;
                bf16x8 wf[2], inf[2];
                #pragma unroll
                for (int jt = 0; jt < 2; ++jt)
                    wf[jt] = *(const bf16x8*)&s_w[((tap * 2 + halfid) * 128 +
                                                   (cog * 2 + jt) * 32 + xlane) * 8];
                #pragma unroll
                for (int it = 0; it < 2; ++it) {
                    int yy = pxg + kh;           // 0..3 within 4-row window
                    int xx = it * 32 + xlane + kw;
                    inf[it] = *(const bf16x8*)&s_in[((halfid * 4 + yy) * 66 + xx) * 8];
                }
                #pragma unroll
                for (int it = 0; it < 2; ++it)
                    #pragma unroll
                    for (int jt = 0; jt < 2; ++jt) {
                        if constexpr (C1)
                            acc[it][jt] = __builtin_amdgcn_mfma_f32_32x32x16_bf16(
                                inf[it], wf[jt], acc[it][jt], 0, 0, 0);
                        else
                            acc[it][jt] = __builtin_amdgcn_mfma_f32_32x32x16_bf16(
                                wf[jt], inf[it], acc[it][jt], 0, 0, 0);
                    }
            }
        __builtin_amdgcn_s_setprio(0);
        __builtin_amdgcn_sched_barrier(0);
        __builtin_amdgcn_s_barrier();            // all waves done reading buffers
        __builtin_amdgcn_sched_barrier(0);
    }

    // ---- epilogue ----
    const int y = y0 + pxg;                      // this wave's single output row
    if constexpr (C1) {
        // D: row = pixel-x, col(lane&31) = co-SLOT. Store compact u; BN via act.
        // Active channel => vector == 1.0, so no vv multiply.
        __bf16* u = (__bf16*)dstv;
        float iv[2], bt[2]; bool on[2]; size_t slb[2];
        #pragma unroll
        for (int jt = 0; jt < 2; ++jt) {
            int slt = co0c + (cog * 2 + jt) * 32 + xlane;
            on[jt] = slt < nact;
            int ch = on[jt] ? act[img * Cc + slt] : 0;
            iv[jt] = binv[ch];
            bt[jt] = bbeta[ch];
            slb[jt] = (size_t)(img * 32 + (slt >> 3)) * SLAB + (slt & 7);
        }
        #pragma unroll
        for (int it = 0; it < 2; ++it) {
            int xb = it * 32;
            #pragma unroll
            for (int reg = 0; reg < 16; ++reg) {
                int x = xb + (reg & 3) + 8 * (reg >> 2) + 4 * halfid;
                if (x < 56) {
                    float mv = maskp[y * 56 + x];
                    int poff = ((y + 1) * PD + (x + 1)) * 8;
                    #pragma unroll
                    for (int jt = 0; jt < 2; ++jt) {
                        if (on[jt]) {
                            float o = fmaxf(fmaf(acc[it][jt][reg], iv[jt], bt[jt]), 0.f) * mv;
                            u[slb[jt] + poff] = (__bf16)o;
                        }
                    }
                }
            }
        }
    } else {
        // D: row = co, col(lane&31) = pixel. Store NCHW f32 + identity+relu.
        float* outp = (float*)dstv;
        int xa[2]; float mva[2]; bool ok[2];
        #pragma unroll
        for (int it = 0; it < 2; ++it) {
            xa[it] = it * 32 + xlane;
            ok[it] = xa[it] < 56;
            mva[it] = ok[it] ? maskp[y * 56 + xa[it]] : 0.f;
        }
        #pragma unroll
        for (int jt = 0; jt < 2; ++jt) {
            int cb = co0c + (cog * 2 + jt) * 32;
            #pragma unroll
            for (int rg = 0; rg < 4; ++rg) {
                int c4 = cb + 8 * rg + 4 * halfid;
                float4 iv4 = *(const float4*)&binv[c4];
                float4 bt4 = *(const float4*)&bbeta[c4];
                float ivv[4] = {iv4.x, iv4.y, iv4.z, iv4.w};
                float btv[4] = {bt4.x, bt4.y, bt4.z, bt4.w};
                #pragma unroll
                for (int j = 0; j < 4; ++j) {
                    int reg = rg * 4 + j;
                    int co = c4 + j;
                    size_t cbase = (size_t)(img * Cc + co) * HW;
                    #pragma unroll
                    for (int it = 0; it < 2; ++it) {
                        if (ok[it]) {
                            size_t oa = cbase + y * 56 + xa[it];
                            float ov = fmaxf(
                                xin[oa] + mva[it] * fmaf(acc[it][jt][reg], ivv[j], btv[j]),
                                0.f);
                            outp[oa] = ov;
                        }
                    }
                }
            }
        }
    }
}

extern "C" void kernel_launch(void* const* d_in, const int* in_sizes, int n_in,
                              void* d_out, int out_size, void* d_ws, size_t ws_size,
                              hipStream_t stream) {
    const float* x    = (const float*)d_in[0];
    const float* mask = (const float*)d_in[1];
    const float* md   = (const float*)d_in[2];
    const float* vec  = (const float*)d_in[3];
    const float* w1   = (const float*)d_in[4];
    const float* bn1g = (const float*)d_in[5];
    const float* bn1b = (const float*)d_in[6];
    const float* bn1m = (const float*)d_in[7];
    const float* bn1v = (const float*)d_in[8];
    const float* w2   = (const float*)d_in[9];
    const float* bn2g = (const float*)d_in[10];
    const float* bn2b = (const float*)d_in[11];
    const float* bn2m = (const float*)d_in[12];
    const float* bn2v = (const float*)d_in[13];
    float* out = (float*)d_out;

    const size_t npad = (size_t)Bn * IMG_ELEMS;  // 27,557,888 elems (55.1 MB bf16)
    __bf16* xm  = (__bf16*)d_ws;
    __bf16* u   = xm + npad;
    __bf16* wp1 = u + npad;
    __bf16* wpT = wp1 + WP_ELEMS;
    int* act    = (int*)(wpT + WP_ELEMS);
    int* meta   = act + Bn * Cc;
    float* binv1  = (float*)(meta + 64);
    float* bbeta1 = binv1 + 256;
    float* binv2  = bbeta1 + 256;
    float* bbeta2 = binv2 + 256;
    __bf16* wp2g = xm;                           // overlay: xm dead after conv1
    __bf16* wp1g = (__bf16*)d_out;               // overlay: out fully overwritten by conv2

    pack_xm<<<dim3(PD, Bn), dim3(256), 0, stream>>>(x, md, xm);
    pack_w1<<<dim3(WP_ELEMS / 256), dim3(256), 0, stream>>>(w1, wp1);
    pack_w2T<<<dim3(WP_ELEMS / 256), dim3(256), 0, stream>>>(w2, wpT);
    cmap_kern<<<dim3(Bn), dim3(64), 0, stream>>>(vec, act, meta);
    zero_u<<<dim3(Bn), dim3(256), 0, stream>>>(u, meta);
    bn_prep<<<dim3(1), dim3(256), 0, stream>>>(bn1g, bn1b, bn1m, bn1v,
                                               bn2g, bn2b, bn2m, bn2v,
                                               binv1, bbeta1, binv2, bbeta2);
    gather_w1<<<dim3(288, Bn), dim3(256), 0, stream>>>(wp1, act, meta, wp1g);

    conv_kern<true><<<dim3(1792), dim3(256), 0, stream>>>(
        xm, wp1g, mask, act, meta, binv1, bbeta1, nullptr, u);
    gather_w2<<<dim3(32, Bn), dim3(256), 0, stream>>>(wpT, act, meta, wp2g);
    conv_kern<false><<<dim3(1792), dim3(256), 0, stream>>>(
        u, wp2g, mask, act, meta, binv2, bbeta2, x, out);
}